// Round 5
// baseline (462.235 us; speedup 1.0000x reference)
//
#include <hip/hip_runtime.h>
#include <hip/hip_bf16.h>

#define T_TOKENS 2048
#define HID 1024
#define ISZ 1408
#define NEXP 8
#define RROWS 5120   // 4096 rows + per-expert 128-alignment padding

typedef __bf16 bf16x8 __attribute__((ext_vector_type(8)));
typedef __bf16 bf16x4 __attribute__((ext_vector_type(4)));
typedef float  f32x4  __attribute__((ext_vector_type(4)));

__device__ __forceinline__ void gload16(const void* g, void* l) {
    __builtin_amdgcn_global_load_lds(
        (const __attribute__((address_space(1))) void*)g,
        (__attribute__((address_space(3))) void*)l,
        16, 0, 0);
}

// counted-vmcnt barrier: my newest stage (N loads) may stay in flight; everything older done.
#define PIPE_BARRIER(N)                                              \
    asm volatile("s_waitcnt vmcnt(" #N ") lgkmcnt(0)" ::: "memory"); \
    __builtin_amdgcn_sched_barrier(0);                               \
    __builtin_amdgcn_s_barrier();                                    \
    __builtin_amdgcn_sched_barrier(0);

// ---------------- Router: one wave per token ----------------
__global__ __launch_bounds__(256) void router_kernel(
    const float* __restrict__ x, const float* __restrict__ gw,
    int* __restrict__ sel, float* __restrict__ wt, int* __restrict__ counts)
{
    __shared__ float sgw[HID * NEXP];  // 32 KB
    for (int i = threadIdx.x; i < HID * NEXP; i += 256) sgw[i] = gw[i];
    __syncthreads();

    const int wave = threadIdx.x >> 6;
    const int lane = threadIdx.x & 63;
    const int t = blockIdx.x * 4 + wave;
    const float* xr = x + (size_t)t * HID;

    const int e = lane & 7;        // expert
    const int c = lane >> 3;       // chunk 0..7 (128 h each)
    float acc = 0.f;
    #pragma unroll 4
    for (int h = c * 128; h < c * 128 + 128; ++h)
        acc += xr[h] * sgw[h * NEXP + e];
    acc += __shfl_xor(acc, 8);
    acc += __shfl_xor(acc, 16);
    acc += __shfl_xor(acc, 32);
    float m = acc;
    #pragma unroll
    for (int d = 1; d < 8; d <<= 1) m = fmaxf(m, __shfl_xor(m, d));
    float p = expf(acc - m);
    float s = p;
    #pragma unroll
    for (int d = 1; d < 8; d <<= 1) s += __shfl_xor(s, d);
    p /= s;
    float p1 = p; int e1 = e;
    #pragma unroll
    for (int d = 1; d < 8; d <<= 1) {
        float op = __shfl_xor(p1, d); int oe = __shfl_xor(e1, d);
        if (op > p1 || (op == p1 && oe < e1)) { p1 = op; e1 = oe; }
    }
    float pm = (e == e1) ? -1.0f : p;
    float p2 = pm; int e2 = e;
    #pragma unroll
    for (int d = 1; d < 8; d <<= 1) {
        float op = __shfl_xor(p2, d); int oe = __shfl_xor(e2, d);
        if (op > p2 || (op == p2 && oe < e2)) { p2 = op; e2 = oe; }
    }
    if (lane == 0) {
        float inv = 1.0f / (p1 + p2);
        sel[t * 2 + 0] = e1; sel[t * 2 + 1] = e2;
        wt[t * 2 + 0] = p1 * inv; wt[t * 2 + 1] = p2 * inv;
        atomicAdd(&counts[e1], 1); atomicAdd(&counts[e2], 1);
    }
}

__global__ void scan_kernel(const int* __restrict__ counts, int* __restrict__ offs,
                            int* __restrict__ ncnt, int* __restrict__ cursor)
{
    if (threadIdx.x == 0 && blockIdx.x == 0) {
        int cur = 0;
        for (int e = 0; e < NEXP; ++e) {
            offs[e] = cur;
            int n = (counts[e] + 127) & ~127;   // 128-row tile alignment
            ncnt[e] = n;
            cursor[e] = 0;
            cur += n;
        }
    }
}

__global__ __launch_bounds__(256) void assign_kernel(
    const int* __restrict__ sel, const float* __restrict__ wt,
    const int* __restrict__ offs, int* __restrict__ cursor,
    int* __restrict__ rtok, float* __restrict__ rwt, int* __restrict__ tok2row)
{
    int t = blockIdx.x * 256 + threadIdx.x;
    if (t >= T_TOKENS) return;
    #pragma unroll
    for (int k = 0; k < 2; ++k) {
        int e = sel[t * 2 + k];
        int pos = atomicAdd(&cursor[e], 1);
        int row = offs[e] + pos;
        rtok[row] = t;
        rwt[row] = wt[t * 2 + k];
        tok2row[t * 2 + k] = row;
    }
}

// ---------------- Gather compacted token rows, fp32 -> bf16 ----------------
__global__ __launch_bounds__(256) void gather_kernel(
    const float* __restrict__ x, const int* __restrict__ rtok, __bf16* __restrict__ xg)
{
    const int row = blockIdx.x;
    const int tid = threadIdx.x;
    const int tok = rtok[row];
    bf16x4 o;
    if (tok >= 0) {
        float4 v = *(const float4*)(x + (size_t)tok * HID + tid * 4);
        o[0] = (__bf16)v.x; o[1] = (__bf16)v.y; o[2] = (__bf16)v.z; o[3] = (__bf16)v.w;
    } else {
        o[0] = (__bf16)0.f; o[1] = (__bf16)0.f; o[2] = (__bf16)0.f; o[3] = (__bf16)0.f;
    }
    *(bf16x4*)(xg + (size_t)row * HID + tid * 4) = o;
}

// ---------------- Transpose + convert: in fp32 [E][R][C] -> out bf16 [E][C][R] ----------------
__global__ __launch_bounds__(256) void tcvt_kernel(
    const float* __restrict__ in, __bf16* __restrict__ out, int R, int C)
{
    const int e = blockIdx.z;
    const float* ine = in + (size_t)e * R * C;
    __bf16* oute = out + (size_t)e * R * C;
    const int r0 = blockIdx.y * 64, c0 = blockIdx.x * 64;
    __shared__ float t[64][65];
    const int tid = threadIdx.x;
    const int lr  = tid >> 4;          // 0..15
    const int lc4 = (tid & 15) * 4;
    #pragma unroll
    for (int p = 0; p < 4; ++p) {
        float4 v = *(const float4*)(ine + (size_t)(r0 + p * 16 + lr) * C + c0 + lc4);
        t[p * 16 + lr][lc4 + 0] = v.x;
        t[p * 16 + lr][lc4 + 1] = v.y;
        t[p * 16 + lr][lc4 + 2] = v.z;
        t[p * 16 + lr][lc4 + 3] = v.w;
    }
    __syncthreads();
    #pragma unroll
    for (int p = 0; p < 4; ++p) {
        int oc = p * 16 + lr;          // local in-col index = out-row
        bf16x4 w;
        #pragma unroll
        for (int j = 0; j < 4; ++j) w[j] = (__bf16)t[lc4 + j][oc];
        *(bf16x4*)(oute + (size_t)(c0 + oc) * R + r0 + lc4) = w;
    }
}

// ---------------- FFN1: inter = silu(xg@WgT') * (xg@WuT') ----------------
// BM=128 x BN=128, BK=32, 4 waves 2x2 (each 64x64), 3-buf depth-2 counted-vmcnt pipeline
__global__ __launch_bounds__(256, 2) void ffn1_kernel(
    const __bf16* __restrict__ xg,
    const __bf16* __restrict__ wgT, const __bf16* __restrict__ wuT,
    const int* __restrict__ offs, const int* __restrict__ ncnt,
    __bf16* __restrict__ inter)
{
    const int e  = blockIdx.x >> 5;
    const int rt = blockIdx.x & 31;
    if (rt * 128 >= ncnt[e]) return;
    const int rowbase = offs[e] + rt * 128;
    const int i0 = blockIdx.y * 128;

    __shared__ __bf16 sA[3][128][32];  // 24 KB
    __shared__ __bf16 sG[3][128][32];  // 24 KB
    __shared__ __bf16 sU[3][128][32];  // 24 KB

    const int tid  = threadIdx.x;
    const int lane = tid & 63;
    const int wid  = tid >> 6;
    const int wr = wid >> 1, wc = wid & 1;
    const int kh = lane >> 4;
    const int ml = lane & 15;

    // staging: tile row = p*64 + wid*16 + srow (p=0,1), col = scol..scol+7
    const int srow = lane >> 2;          // 0..15
    const int scol = (lane & 3) * 8;     // bf16 elems
    const __bf16* Ab = xg + (size_t)(rowbase + wid * 16 + srow) * HID + scol;
    const size_t woff = (size_t)e * ISZ * HID + (size_t)(i0 + wid * 16 + srow) * HID + scol;
    const __bf16* Gb = wgT + woff;
    const __bf16* Ub = wuT + woff;
    const size_t half = (size_t)64 * HID;   // +64 tile rows

    f32x4 accg[4][4], accu[4][4];
    #pragma unroll
    for (int m = 0; m < 4; ++m)
        #pragma unroll
        for (int n = 0; n < 4; ++n) { accg[m][n] = (f32x4){0,0,0,0}; accu[m][n] = (f32x4){0,0,0,0}; }

    auto stage = [&](int b, int k0) {   // 6 gload16 per wave
        gload16(Ab + k0,        &sA[b][wid * 16][0]);
        gload16(Ab + k0 + half, &sA[b][64 + wid * 16][0]);
        gload16(Gb + k0,        &sG[b][wid * 16][0]);
        gload16(Gb + k0 + half, &sG[b][64 + wid * 16][0]);
        gload16(Ub + k0,        &sU[b][wid * 16][0]);
        gload16(Ub + k0 + half, &sU[b][64 + wid * 16][0]);
    };
    auto compute = [&](int b) {
        bf16x8 a_[4], g_[4], u_[4];
        #pragma unroll
        for (int m = 0; m < 4; ++m) a_[m] = *(const bf16x8*)&sA[b][wr * 64 + m * 16 + ml][kh * 8];
        #pragma unroll
        for (int n = 0; n < 4; ++n) {
            g_[n] = *(const bf16x8*)&sG[b][wc * 64 + n * 16 + ml][kh * 8];
            u_[n] = *(const bf16x8*)&sU[b][wc * 64 + n * 16 + ml][kh * 8];
        }
        #pragma unroll
        for (int m = 0; m < 4; ++m)
            #pragma unroll
            for (int n = 0; n < 4; ++n) {
                accg[m][n] = __builtin_amdgcn_mfma_f32_16x16x32_bf16(a_[m], g_[n], accg[m][n], 0, 0, 0);
                accu[m][n] = __builtin_amdgcn_mfma_f32_16x16x32_bf16(a_[m], u_[n], accu[m][n], 0, 0, 0);
            }
    };

    const int nIter = HID / 32;   // 32
    stage(0, 0);
    stage(1, 32);
    PIPE_BARRIER(6)               // stage0 complete -> buf0 ready
    for (int i = 0; i < nIter; ++i) {
        int ks = (i + 2 < nIter) ? (i + 2) * 32 : 0;   // clamped dead stage keeps counts uniform
        stage((i + 2) % 3, ks);
        compute(i % 3);
        PIPE_BARRIER(6)           // newest stage in flight; buf i+1 ready; ds_reads drained
    }

    #pragma unroll
    for (int m = 0; m < 4; ++m)
        #pragma unroll
        for (int n = 0; n < 4; ++n)
            #pragma unroll
            for (int r = 0; r < 4; ++r) {
                float gv = accg[m][n][r];
                float uv = accu[m][n][r];
                float v = gv / (1.0f + __expf(-gv)) * uv;
                int row = rowbase + wr * 64 + m * 16 + kh * 4 + r;  // D row = (lane>>4)*4 + reg
                int col = i0 + wc * 64 + n * 16 + ml;               // D col = lane&15
                inter[(size_t)row * ISZ + col] = (__bf16)v;
            }
}

// ---------------- FFN2: y[row] = rwt[row] * (inter[row] @ WdT')  (no atomics) ----------------
// BM=128 x BN=128, BK=32, 4 waves 2x2, 3-buf depth-2 counted-vmcnt pipeline
__global__ __launch_bounds__(256, 2) void ffn2_kernel(
    const __bf16* __restrict__ inter, const __bf16* __restrict__ wdT,
    const float* __restrict__ rwt,
    const int* __restrict__ offs, const int* __restrict__ ncnt,
    float* __restrict__ y)
{
    const int e  = blockIdx.x >> 5;
    const int rt = blockIdx.x & 31;
    if (rt * 128 >= ncnt[e]) return;
    const int rowbase = offs[e] + rt * 128;
    const int n0 = blockIdx.y * 128;

    __shared__ __bf16 sA[3][128][32];  // 24 KB
    __shared__ __bf16 sB[3][128][32];  // 24 KB

    const int tid  = threadIdx.x;
    const int lane = tid & 63;
    const int wid  = tid >> 6;
    const int wr = wid >> 1, wc = wid & 1;
    const int kh = lane >> 4;
    const int ml = lane & 15;

    const int srow = lane >> 2;
    const int scol = (lane & 3) * 8;
    const __bf16* Ab = inter + (size_t)(rowbase + wid * 16 + srow) * ISZ + scol;
    const __bf16* Bb = wdT + (size_t)e * HID * ISZ + (size_t)(n0 + wid * 16 + srow) * ISZ + scol;
    const size_t halfA = (size_t)64 * ISZ;
    const size_t halfB = (size_t)64 * ISZ;

    f32x4 acc[4][4];
    #pragma unroll
    for (int m = 0; m < 4; ++m)
        #pragma unroll
        for (int n = 0; n < 4; ++n) acc[m][n] = (f32x4){0,0,0,0};

    auto stage = [&](int b, int k0) {   // 4 gload16 per wave
        gload16(Ab + k0,         &sA[b][wid * 16][0]);
        gload16(Ab + k0 + halfA, &sA[b][64 + wid * 16][0]);
        gload16(Bb + k0,         &sB[b][wid * 16][0]);
        gload16(Bb + k0 + halfB, &sB[b][64 + wid * 16][0]);
    };
    auto compute = [&](int b) {
        bf16x8 a_[4], b_[4];
        #pragma unroll
        for (int m = 0; m < 4; ++m) a_[m] = *(const bf16x8*)&sA[b][wr * 64 + m * 16 + ml][kh * 8];
        #pragma unroll
        for (int n = 0; n < 4; ++n) b_[n] = *(const bf16x8*)&sB[b][wc * 64 + n * 16 + ml][kh * 8];
        #pragma unroll
        for (int m = 0; m < 4; ++m)
            #pragma unroll
            for (int n = 0; n < 4; ++n)
                acc[m][n] = __builtin_amdgcn_mfma_f32_16x16x32_bf16(a_[m], b_[n], acc[m][n], 0, 0, 0);
    };

    const int nIter = ISZ / 32;   // 44
    stage(0, 0);
    stage(1, 32);
    PIPE_BARRIER(4)
    for (int i = 0; i < nIter; ++i) {
        int ks = (i + 2 < nIter) ? (i + 2) * 32 : 0;
        stage((i + 2) % 3, ks);
        compute(i % 3);
        PIPE_BARRIER(4)
    }

    #pragma unroll
    for (int m = 0; m < 4; ++m)
        #pragma unroll
        for (int n = 0; n < 4; ++n)
            #pragma unroll
            for (int r = 0; r < 4; ++r) {
                int row = rowbase + wr * 64 + m * 16 + kh * 4 + r;
                float v = rwt[row] * acc[m][n][r];
                y[(size_t)row * HID + n0 + wc * 64 + n * 16 + ml] = v;
            }
}

// ---------------- Combine: out[t] = y[row0(t)] + y[row1(t)] ----------------
__global__ __launch_bounds__(256) void combine_kernel(
    const float* __restrict__ y, const int* __restrict__ tok2row, float* __restrict__ out)
{
    const int idx = blockIdx.x * 256 + threadIdx.x;   // over T_TOKENS * HID/4
    const int t = idx >> 8;           // HID/4 = 256 float4 per token
    const int c = (idx & 255) * 4;
    const int r0 = tok2row[t * 2];
    const int r1 = tok2row[t * 2 + 1];
    float4 a = *(const float4*)(y + (size_t)r0 * HID + c);
    float4 b = *(const float4*)(y + (size_t)r1 * HID + c);
    float4 o = {a.x + b.x, a.y + b.y, a.z + b.z, a.w + b.w};
    *(float4*)(out + (size_t)t * HID + c) = o;
}

extern "C" void kernel_launch(void* const* d_in, const int* in_sizes, int n_in,
                              void* d_out, int out_size, void* d_ws, size_t ws_size,
                              hipStream_t stream) {
    const float* x  = (const float*)d_in[0];
    const float* gw = (const float*)d_in[1];
    const float* wg = (const float*)d_in[2];
    const float* wu = (const float*)d_in[3];
    const float* wd = (const float*)d_in[4];
    float* out = (float*)d_out;

    char* ws = (char*)d_ws;
    int*    counts  = (int*)(ws + 0);
    int*    cursor  = (int*)(ws + 32);
    int*    offs    = (int*)(ws + 64);
    int*    ncnt    = (int*)(ws + 96);
    int*    sel     = (int*)(ws + 128);                 // 4096 int
    float*  wtp     = (float*)(ws + 16512);             // 4096 f32
    int*    rtok    = (int*)(ws + 32896);               // 5120 int
    float*  rwt     = (float*)(ws + 53376);             // 5120 f32
    int*    tok2row = (int*)(ws + 73856);               // 4096 int
    __bf16* xg      = (__bf16*)(ws + 90240);            // 5120*1024 bf16 = 10.49 MB
    __bf16* inter   = (__bf16*)(ws + 10576000);         // 5120*1408 bf16 = 14.42 MB
    __bf16* wgT     = (__bf16*)(ws + 24993920);         // 8*1408*1024 bf16 = 23.07 MB
    __bf16* wuT     = (__bf16*)(ws + 48062592);         // 23.07 MB
    __bf16* wdT     = (__bf16*)(ws + 71131264);         // 23.07 MB -> total 94.2 MB
    float*  y       = (float*)wgT;                      // alias: wgT dead after ffn1; 21.0 MB <= 23.07 MB

    hipMemsetAsync(counts, 0, 32, stream);
    hipMemsetAsync(rtok, 0xFF, RROWS * 4, stream);

    tcvt_kernel<<<dim3(ISZ / 64, HID / 64, NEXP), 256, 0, stream>>>(wg, wgT, HID, ISZ);
    tcvt_kernel<<<dim3(ISZ / 64, HID / 64, NEXP), 256, 0, stream>>>(wu, wuT, HID, ISZ);
    tcvt_kernel<<<dim3(HID / 64, ISZ / 64, NEXP), 256, 0, stream>>>(wd, wdT, ISZ, HID);

    router_kernel<<<T_TOKENS / 4, 256, 0, stream>>>(x, gw, sel, wtp, counts);
    scan_kernel<<<1, 64, 0, stream>>>(counts, offs, ncnt, cursor);
    assign_kernel<<<(T_TOKENS + 255) / 256, 256, 0, stream>>>(sel, wtp, offs, cursor, rtok, rwt, tok2row);
    gather_kernel<<<RROWS, 256, 0, stream>>>(x, rtok, xg);

    ffn1_kernel<<<dim3(NEXP * 32, ISZ / 128), 256, 0, stream>>>(xg, wgT, wuT, offs, ncnt, inter);
    ffn2_kernel<<<dim3(NEXP * 32, HID / 128), 256, 0, stream>>>(inter, wdT, rwt, offs, ncnt, y);
    combine_kernel<<<(T_TOKENS * HID / 4) / 256, 256, 0, stream>>>(y, tok2row, out);
}

// Round 6
// 255.518 us; speedup vs baseline: 1.8090x; 1.8090x over previous
//
#include <hip/hip_runtime.h>
#include <hip/hip_bf16.h>

#define T_TOKENS 2048
#define HID 1024
#define ISZ 1408
#define NEXP 8
#define RROWS 5120   // 4096 rows + per-expert 64-alignment padding

typedef __bf16 bf16x8 __attribute__((ext_vector_type(8)));
typedef __bf16 bf16x4 __attribute__((ext_vector_type(4)));
typedef float  f32x4  __attribute__((ext_vector_type(4)));

__device__ __forceinline__ void gload16(const void* g, void* l) {
    __builtin_amdgcn_global_load_lds(
        (const __attribute__((address_space(1))) void*)g,
        (__attribute__((address_space(3))) void*)l,
        16, 0, 0);
}

// counted-vmcnt barrier: newest N loads may stay in flight; everything older done.
#define PIPE_BARRIER(N)                                              \
    asm volatile("s_waitcnt vmcnt(" #N ") lgkmcnt(0)" ::: "memory"); \
    __builtin_amdgcn_sched_barrier(0);                               \
    __builtin_amdgcn_s_barrier();                                    \
    __builtin_amdgcn_sched_barrier(0);

// ---------------- Router: one wave per token ----------------
__global__ __launch_bounds__(256) void router_kernel(
    const float* __restrict__ x, const float* __restrict__ gw,
    int* __restrict__ sel, float* __restrict__ wt, int* __restrict__ counts)
{
    __shared__ float sgw[HID * NEXP];  // 32 KB
    for (int i = threadIdx.x; i < HID * NEXP; i += 256) sgw[i] = gw[i];
    __syncthreads();

    const int wave = threadIdx.x >> 6;
    const int lane = threadIdx.x & 63;
    const int t = blockIdx.x * 4 + wave;
    const float* xr = x + (size_t)t * HID;

    const int e = lane & 7;        // expert
    const int c = lane >> 3;       // chunk 0..7 (128 h each)
    float acc = 0.f;
    #pragma unroll 4
    for (int h = c * 128; h < c * 128 + 128; ++h)
        acc += xr[h] * sgw[h * NEXP + e];
    acc += __shfl_xor(acc, 8);
    acc += __shfl_xor(acc, 16);
    acc += __shfl_xor(acc, 32);
    float m = acc;
    #pragma unroll
    for (int d = 1; d < 8; d <<= 1) m = fmaxf(m, __shfl_xor(m, d));
    float p = expf(acc - m);
    float s = p;
    #pragma unroll
    for (int d = 1; d < 8; d <<= 1) s += __shfl_xor(s, d);
    p /= s;
    float p1 = p; int e1 = e;
    #pragma unroll
    for (int d = 1; d < 8; d <<= 1) {
        float op = __shfl_xor(p1, d); int oe = __shfl_xor(e1, d);
        if (op > p1 || (op == p1 && oe < e1)) { p1 = op; e1 = oe; }
    }
    float pm = (e == e1) ? -1.0f : p;
    float p2 = pm; int e2 = e;
    #pragma unroll
    for (int d = 1; d < 8; d <<= 1) {
        float op = __shfl_xor(p2, d); int oe = __shfl_xor(e2, d);
        if (op > p2 || (op == p2 && oe < e2)) { p2 = op; e2 = oe; }
    }
    if (lane == 0) {
        float inv = 1.0f / (p1 + p2);
        sel[t * 2 + 0] = e1; sel[t * 2 + 1] = e2;
        wt[t * 2 + 0] = p1 * inv; wt[t * 2 + 1] = p2 * inv;
        atomicAdd(&counts[e1], 1); atomicAdd(&counts[e2], 1);
    }
}

__global__ void scan_kernel(const int* __restrict__ counts, int* __restrict__ offs,
                            int* __restrict__ ncnt, int* __restrict__ cursor)
{
    if (threadIdx.x == 0 && blockIdx.x == 0) {
        int cur = 0;
        for (int e = 0; e < NEXP; ++e) {
            offs[e] = cur;
            int n = (counts[e] + 63) & ~63;   // 64-row tile alignment
            ncnt[e] = n;
            cursor[e] = 0;
            cur += n;
        }
    }
}

__global__ __launch_bounds__(256) void assign_kernel(
    const int* __restrict__ sel, const float* __restrict__ wt,
    const int* __restrict__ offs, int* __restrict__ cursor,
    int* __restrict__ rtok, float* __restrict__ rwt, int* __restrict__ tok2row)
{
    int t = blockIdx.x * 256 + threadIdx.x;
    if (t >= T_TOKENS) return;
    #pragma unroll
    for (int k = 0; k < 2; ++k) {
        int e = sel[t * 2 + k];
        int pos = atomicAdd(&cursor[e], 1);
        int row = offs[e] + pos;
        rtok[row] = t;
        rwt[row] = wt[t * 2 + k];
        tok2row[t * 2 + k] = row;
    }
}

// ---------------- Gather compacted token rows, fp32 -> bf16 ----------------
__global__ __launch_bounds__(256) void gather_kernel(
    const float* __restrict__ x, const int* __restrict__ rtok, __bf16* __restrict__ xg)
{
    const int row = blockIdx.x;
    const int tid = threadIdx.x;
    const int tok = rtok[row];
    bf16x4 o;
    if (tok >= 0) {
        float4 v = *(const float4*)(x + (size_t)tok * HID + tid * 4);
        o[0] = (__bf16)v.x; o[1] = (__bf16)v.y; o[2] = (__bf16)v.z; o[3] = (__bf16)v.w;
    } else {
        o[0] = (__bf16)0.f; o[1] = (__bf16)0.f; o[2] = (__bf16)0.f; o[3] = (__bf16)0.f;
    }
    *(bf16x4*)(xg + (size_t)row * HID + tid * 4) = o;
}

// ---------------- Transpose + convert: in fp32 [E][R][C] -> out bf16 [E][C][R] ----------------
__global__ __launch_bounds__(256) void tcvt_kernel(
    const float* __restrict__ in, __bf16* __restrict__ out, int R, int C)
{
    const int e = blockIdx.z;
    const float* ine = in + (size_t)e * R * C;
    __bf16* oute = out + (size_t)e * R * C;
    const int r0 = blockIdx.y * 64, c0 = blockIdx.x * 64;
    __shared__ float t[64][65];
    const int tid = threadIdx.x;
    const int lr  = tid >> 4;          // 0..15
    const int lc4 = (tid & 15) * 4;
    #pragma unroll
    for (int p = 0; p < 4; ++p) {
        float4 v = *(const float4*)(ine + (size_t)(r0 + p * 16 + lr) * C + c0 + lc4);
        t[p * 16 + lr][lc4 + 0] = v.x;
        t[p * 16 + lr][lc4 + 1] = v.y;
        t[p * 16 + lr][lc4 + 2] = v.z;
        t[p * 16 + lr][lc4 + 3] = v.w;
    }
    __syncthreads();
    #pragma unroll
    for (int p = 0; p < 4; ++p) {
        int oc = p * 16 + lr;          // local in-col index = out-row
        bf16x4 w;
        #pragma unroll
        for (int j = 0; j < 4; ++j) w[j] = (__bf16)t[lc4 + j][oc];
        *(bf16x4*)(oute + (size_t)(c0 + oc) * R + r0 + lc4) = w;
    }
}

// ---------------- FFN1: inter = silu(xg@WgT') * (xg@WuT') ----------------
// BM=64 x BN=64(G)+64(U), BK=32, 4 waves 2x2, 4-buf depth-3 counted-vmcnt pipeline,
// source-chunk XOR swizzle (LDS bank fix), XCD-chunked block swizzle.
__global__ __launch_bounds__(256) void ffn1_kernel(
    const __bf16* __restrict__ xg,
    const __bf16* __restrict__ wgT, const __bf16* __restrict__ wuT,
    const int* __restrict__ offs, const int* __restrict__ ncnt,
    __bf16* __restrict__ inter)
{
    // flat grid 5632 = 8 XCD chunks of 704; consecutive per-XCD blocks share (e,i0) weight panel
    const int n  = blockIdx.x;
    const int nn = (n & 7) * 704 + (n >> 3);
    const int i0 = (nn >> 8) * 64;          // 22 stripes
    const int xr = nn & 255;
    const int e  = xr >> 5;
    const int rt = xr & 31;
    if (rt * 64 >= ncnt[e]) return;
    const int rowbase = offs[e] + rt * 64;

    __shared__ __bf16 sA[4][64][32];   // 16 KB
    __shared__ __bf16 sG[4][64][32];   // 16 KB
    __shared__ __bf16 sU[4][64][32];   // 16 KB

    const int tid  = threadIdx.x;
    const int lane = tid & 63;
    const int wid  = tid >> 6;
    const int wr = wid >> 1, wc = wid & 1;
    const int kh = lane >> 4;
    const int ml = lane & 15;

    // staging: LDS slot (row = lane>>2, chunk = lane&3) holds global chunk (lane&3)^(row&3)
    const int srow = lane >> 2;                          // 0..15
    const int sc   = (((lane & 3) ^ (srow & 3)) * 8);    // swizzled source col (bf16 elems)
    const __bf16* Ab = xg + (size_t)(rowbase + wid * 16 + srow) * HID + sc;
    const size_t woff = (size_t)e * ISZ * HID + (size_t)(i0 + wid * 16 + srow) * HID + sc;
    const __bf16* Gb = wgT + woff;
    const __bf16* Ub = wuT + woff;

    f32x4 accg[2][2], accu[2][2];
    #pragma unroll
    for (int m = 0; m < 2; ++m)
        #pragma unroll
        for (int q = 0; q < 2; ++q) { accg[m][q] = (f32x4){0,0,0,0}; accu[m][q] = (f32x4){0,0,0,0}; }

    auto stage = [&](int b, int k0) {   // 3 gload16 per wave
        gload16(Ab + k0, &sA[b][wid * 16][0]);
        gload16(Gb + k0, &sG[b][wid * 16][0]);
        gload16(Ub + k0, &sU[b][wid * 16][0]);
    };
    const int ca = (kh ^ (ml & 3)) * 8;   // swizzled read col: global chunk kh of row (row&3 == ml&3)
    auto compute = [&](int b) {
        bf16x8 a_[2], g_[2], u_[2];
        #pragma unroll
        for (int m = 0; m < 2; ++m) a_[m] = *(const bf16x8*)&sA[b][wr * 32 + m * 16 + ml][ca];
        #pragma unroll
        for (int q = 0; q < 2; ++q) {
            g_[q] = *(const bf16x8*)&sG[b][wc * 32 + q * 16 + ml][ca];
            u_[q] = *(const bf16x8*)&sU[b][wc * 32 + q * 16 + ml][ca];
        }
        #pragma unroll
        for (int m = 0; m < 2; ++m)
            #pragma unroll
            for (int q = 0; q < 2; ++q) {
                accg[m][q] = __builtin_amdgcn_mfma_f32_16x16x32_bf16(a_[m], g_[q], accg[m][q], 0, 0, 0);
                accu[m][q] = __builtin_amdgcn_mfma_f32_16x16x32_bf16(a_[m], u_[q], accu[m][q], 0, 0, 0);
            }
    };

    const int nIter = HID / 32;   // 32
    stage(0, 0);
    stage(1, 32);
    stage(2, 64);
    PIPE_BARRIER(6)               // stage0 done -> buf0 ready; stages 1,2 (6 loads) in flight
    for (int i = 0; i < nIter; ++i) {
        int ks = (i + 3 < nIter) ? (i + 3) * 32 : 0;   // clamped dead stage keeps counts uniform
        stage((i + 3) & 3, ks);
        compute(i & 3);
        PIPE_BARRIER(6)           // 2 newest stages in flight; buf i+1 ready; ds_reads drained
    }

    #pragma unroll
    for (int m = 0; m < 2; ++m)
        #pragma unroll
        for (int q = 0; q < 2; ++q)
            #pragma unroll
            for (int r = 0; r < 4; ++r) {
                float gv = accg[m][q][r];
                float uv = accu[m][q][r];
                float v = gv / (1.0f + __expf(-gv)) * uv;
                int row = rowbase + wr * 32 + m * 16 + kh * 4 + r;  // D row = (lane>>4)*4 + reg
                int col = i0 + wc * 32 + q * 16 + ml;               // D col = lane&15
                inter[(size_t)row * ISZ + col] = (__bf16)v;
            }
}

// ---------------- FFN2: y[row] = rwt[row] * (inter[row] @ WdT')  (no atomics) ----------------
// BM=64 x BN=64, BK=32, 4 waves 2x2, 4-buf depth-3 pipeline, same swizzles.
__global__ __launch_bounds__(256) void ffn2_kernel(
    const __bf16* __restrict__ inter, const __bf16* __restrict__ wdT,
    const float* __restrict__ rwt,
    const int* __restrict__ offs, const int* __restrict__ ncnt,
    float* __restrict__ y)
{
    // flat grid 4096 = 8 XCD chunks of 512
    const int n  = blockIdx.x;
    const int nn = (n & 7) * 512 + (n >> 3);
    const int n0 = (nn >> 8) * 64;          // 16 stripes
    const int xr = nn & 255;
    const int e  = xr >> 5;
    const int rt = xr & 31;
    if (rt * 64 >= ncnt[e]) return;
    const int rowbase = offs[e] + rt * 64;

    __shared__ __bf16 sA[4][64][32];   // 16 KB
    __shared__ __bf16 sB[4][64][32];   // 16 KB

    const int tid  = threadIdx.x;
    const int lane = tid & 63;
    const int wid  = tid >> 6;
    const int wr = wid >> 1, wc = wid & 1;
    const int kh = lane >> 4;
    const int ml = lane & 15;

    const int srow = lane >> 2;
    const int sc   = (((lane & 3) ^ (srow & 3)) * 8);
    const __bf16* Ab = inter + (size_t)(rowbase + wid * 16 + srow) * ISZ + sc;
    const __bf16* Bb = wdT + (size_t)e * HID * ISZ + (size_t)(n0 + wid * 16 + srow) * ISZ + sc;

    f32x4 acc[2][2];
    #pragma unroll
    for (int m = 0; m < 2; ++m)
        #pragma unroll
        for (int q = 0; q < 2; ++q) acc[m][q] = (f32x4){0,0,0,0};

    auto stage = [&](int b, int k0) {   // 2 gload16 per wave
        gload16(Ab + k0, &sA[b][wid * 16][0]);
        gload16(Bb + k0, &sB[b][wid * 16][0]);
    };
    const int ca = (kh ^ (ml & 3)) * 8;
    auto compute = [&](int b) {
        bf16x8 a_[2], b_[2];
        #pragma unroll
        for (int m = 0; m < 2; ++m) a_[m] = *(const bf16x8*)&sA[b][wr * 32 + m * 16 + ml][ca];
        #pragma unroll
        for (int q = 0; q < 2; ++q) b_[q] = *(const bf16x8*)&sB[b][wc * 32 + q * 16 + ml][ca];
        #pragma unroll
        for (int m = 0; m < 2; ++m)
            #pragma unroll
            for (int q = 0; q < 2; ++q)
                acc[m][q] = __builtin_amdgcn_mfma_f32_16x16x32_bf16(a_[m], b_[q], acc[m][q], 0, 0, 0);
    };

    const int nIter = ISZ / 32;   // 44
    stage(0, 0);
    stage(1, 32);
    stage(2, 64);
    PIPE_BARRIER(4)
    for (int i = 0; i < nIter; ++i) {
        int ks = (i + 3 < nIter) ? (i + 3) * 32 : 0;
        stage((i + 3) & 3, ks);
        compute(i & 3);
        PIPE_BARRIER(4)
    }

    #pragma unroll
    for (int m = 0; m < 2; ++m)
        #pragma unroll
        for (int q = 0; q < 2; ++q)
            #pragma unroll
            for (int r = 0; r < 4; ++r) {
                int row = rowbase + wr * 32 + m * 16 + kh * 4 + r;
                float v = rwt[row] * acc[m][q][r];
                y[(size_t)row * HID + n0 + wc * 32 + q * 16 + ml] = v;
            }
}

// ---------------- Combine: out[t] = y[row0(t)] + y[row1(t)] ----------------
__global__ __launch_bounds__(256) void combine_kernel(
    const float* __restrict__ y, const int* __restrict__ tok2row, float* __restrict__ out)
{
    const int idx = blockIdx.x * 256 + threadIdx.x;   // over T_TOKENS * HID/4
    const int t = idx >> 8;           // HID/4 = 256 float4 per token
    const int c = (idx & 255) * 4;
    const int r0 = tok2row[t * 2];
    const int r1 = tok2row[t * 2 + 1];
    float4 a = *(const float4*)(y + (size_t)r0 * HID + c);
    float4 b = *(const float4*)(y + (size_t)r1 * HID + c);
    float4 o = {a.x + b.x, a.y + b.y, a.z + b.z, a.w + b.w};
    *(float4*)(out + (size_t)t * HID + c) = o;
}

extern "C" void kernel_launch(void* const* d_in, const int* in_sizes, int n_in,
                              void* d_out, int out_size, void* d_ws, size_t ws_size,
                              hipStream_t stream) {
    const float* x  = (const float*)d_in[0];
    const float* gw = (const float*)d_in[1];
    const float* wg = (const float*)d_in[2];
    const float* wu = (const float*)d_in[3];
    const float* wd = (const float*)d_in[4];
    float* out = (float*)d_out;

    char* ws = (char*)d_ws;
    int*    counts  = (int*)(ws + 0);
    int*    cursor  = (int*)(ws + 32);
    int*    offs    = (int*)(ws + 64);
    int*    ncnt    = (int*)(ws + 96);
    int*    sel     = (int*)(ws + 128);                 // 4096 int
    float*  wtp     = (float*)(ws + 16512);             // 4096 f32
    int*    rtok    = (int*)(ws + 32896);               // 5120 int
    float*  rwt     = (float*)(ws + 53376);             // 5120 f32
    int*    tok2row = (int*)(ws + 73856);               // 4096 int
    __bf16* xg      = (__bf16*)(ws + 90240);            // 5120*1024 bf16 = 10.49 MB
    __bf16* inter   = (__bf16*)(ws + 10576000);         // 5120*1408 bf16 = 14.42 MB
    __bf16* wgT     = (__bf16*)(ws + 24993920);         // 8*1408*1024 bf16 = 23.07 MB
    __bf16* wuT     = (__bf16*)(ws + 48062592);         // 23.07 MB
    __bf16* wdT     = (__bf16*)(ws + 71131264);         // 23.07 MB -> total 94.2 MB
    float*  y       = (float*)wgT;                      // alias: wgT dead after ffn1; 21.0 MB <= 23.07 MB

    hipMemsetAsync(counts, 0, 32, stream);
    hipMemsetAsync(rtok, 0xFF, RROWS * 4, stream);

    tcvt_kernel<<<dim3(ISZ / 64, HID / 64, NEXP), 256, 0, stream>>>(wg, wgT, HID, ISZ);
    tcvt_kernel<<<dim3(ISZ / 64, HID / 64, NEXP), 256, 0, stream>>>(wu, wuT, HID, ISZ);
    tcvt_kernel<<<dim3(HID / 64, ISZ / 64, NEXP), 256, 0, stream>>>(wd, wdT, ISZ, HID);

    router_kernel<<<T_TOKENS / 4, 256, 0, stream>>>(x, gw, sel, wtp, counts);
    scan_kernel<<<1, 64, 0, stream>>>(counts, offs, ncnt, cursor);
    assign_kernel<<<(T_TOKENS + 255) / 256, 256, 0, stream>>>(sel, wtp, offs, cursor, rtok, rwt, tok2row);
    gather_kernel<<<RROWS, 256, 0, stream>>>(x, rtok, xg);

    ffn1_kernel<<<8 * 704, 256, 0, stream>>>(xg, wgT, wuT, offs, ncnt, inter);   // 5632 = 256 x 22
    ffn2_kernel<<<8 * 512, 256, 0, stream>>>(inter, wdT, rwt, offs, ncnt, y);    // 4096 = 256 x 16
    combine_kernel<<<(T_TOKENS * HID / 4) / 256, 256, 0, stream>>>(y, tok2row, out);
}

// Round 7
// 230.314 us; speedup vs baseline: 2.0070x; 1.1094x over previous
//
#include <hip/hip_runtime.h>
#include <hip/hip_bf16.h>

#define T_TOKENS 2048
#define HID 1024
#define ISZ 1408
#define NEXP 8
#define RROWS 5120   // 4096 rows + per-expert 64-alignment padding

typedef __bf16 bf16x8 __attribute__((ext_vector_type(8)));
typedef __bf16 bf16x4 __attribute__((ext_vector_type(4)));
typedef float  f32x4  __attribute__((ext_vector_type(4)));

__device__ __forceinline__ void gload16(const void* g, void* l) {
    __builtin_amdgcn_global_load_lds(
        (const __attribute__((address_space(1))) void*)g,
        (__attribute__((address_space(3))) void*)l,
        16, 0, 0);
}

// counted-vmcnt barrier: newest N loads may stay in flight; everything older done.
#define PIPE_BARRIER(N)                                              \
    asm volatile("s_waitcnt vmcnt(" #N ") lgkmcnt(0)" ::: "memory"); \
    __builtin_amdgcn_sched_barrier(0);                               \
    __builtin_amdgcn_s_barrier();                                    \
    __builtin_amdgcn_sched_barrier(0);

// ---------------- Router: one wave per token ----------------
__global__ __launch_bounds__(256) void router_kernel(
    const float* __restrict__ x, const float* __restrict__ gw,
    int* __restrict__ sel, float* __restrict__ wt, int* __restrict__ counts)
{
    __shared__ float sgw[HID * NEXP];  // 32 KB
    for (int i = threadIdx.x; i < HID * NEXP; i += 256) sgw[i] = gw[i];
    __syncthreads();

    const int wave = threadIdx.x >> 6;
    const int lane = threadIdx.x & 63;
    const int t = blockIdx.x * 4 + wave;
    const float* xr = x + (size_t)t * HID;

    const int e = lane & 7;        // expert
    const int c = lane >> 3;       // chunk 0..7 (128 h each)
    float acc = 0.f;
    #pragma unroll 4
    for (int h = c * 128; h < c * 128 + 128; ++h)
        acc += xr[h] * sgw[h * NEXP + e];
    acc += __shfl_xor(acc, 8);
    acc += __shfl_xor(acc, 16);
    acc += __shfl_xor(acc, 32);
    float m = acc;
    #pragma unroll
    for (int d = 1; d < 8; d <<= 1) m = fmaxf(m, __shfl_xor(m, d));
    float p = expf(acc - m);
    float s = p;
    #pragma unroll
    for (int d = 1; d < 8; d <<= 1) s += __shfl_xor(s, d);
    p /= s;
    float p1 = p; int e1 = e;
    #pragma unroll
    for (int d = 1; d < 8; d <<= 1) {
        float op = __shfl_xor(p1, d); int oe = __shfl_xor(e1, d);
        if (op > p1 || (op == p1 && oe < e1)) { p1 = op; e1 = oe; }
    }
    float pm = (e == e1) ? -1.0f : p;
    float p2 = pm; int e2 = e;
    #pragma unroll
    for (int d = 1; d < 8; d <<= 1) {
        float op = __shfl_xor(p2, d); int oe = __shfl_xor(e2, d);
        if (op > p2 || (op == p2 && oe < e2)) { p2 = op; e2 = oe; }
    }
    if (lane == 0) {
        float inv = 1.0f / (p1 + p2);
        sel[t * 2 + 0] = e1; sel[t * 2 + 1] = e2;
        wt[t * 2 + 0] = p1 * inv; wt[t * 2 + 1] = p2 * inv;
        atomicAdd(&counts[e1], 1); atomicAdd(&counts[e2], 1);
    }
}

__global__ void scan_kernel(const int* __restrict__ counts, int* __restrict__ offs,
                            int* __restrict__ ncnt, int* __restrict__ cursor)
{
    if (threadIdx.x == 0 && blockIdx.x == 0) {
        int cur = 0;
        for (int e = 0; e < NEXP; ++e) {
            offs[e] = cur;
            int n = (counts[e] + 63) & ~63;   // 64-row tile alignment
            ncnt[e] = n;
            cursor[e] = 0;
            cur += n;
        }
    }
}

__global__ __launch_bounds__(256) void assign_kernel(
    const int* __restrict__ sel, const float* __restrict__ wt,
    const int* __restrict__ offs, int* __restrict__ cursor,
    int* __restrict__ rtok, float* __restrict__ rwt, int* __restrict__ tok2row)
{
    int t = blockIdx.x * 256 + threadIdx.x;
    if (t >= T_TOKENS) return;
    #pragma unroll
    for (int k = 0; k < 2; ++k) {
        int e = sel[t * 2 + k];
        int pos = atomicAdd(&cursor[e], 1);
        int row = offs[e] + pos;
        rtok[row] = t;
        rwt[row] = wt[t * 2 + k];
        tok2row[t * 2 + k] = row;
    }
}

// ---------------- Gather compacted token rows, fp32 -> bf16 ----------------
__global__ __launch_bounds__(256) void gather_kernel(
    const float* __restrict__ x, const int* __restrict__ rtok, __bf16* __restrict__ xg)
{
    const int row = blockIdx.x;
    const int tid = threadIdx.x;
    const int tok = rtok[row];
    bf16x4 o;
    if (tok >= 0) {
        float4 v = *(const float4*)(x + (size_t)tok * HID + tid * 4);
        o[0] = (__bf16)v.x; o[1] = (__bf16)v.y; o[2] = (__bf16)v.z; o[3] = (__bf16)v.w;
    } else {
        o[0] = (__bf16)0.f; o[1] = (__bf16)0.f; o[2] = (__bf16)0.f; o[3] = (__bf16)0.f;
    }
    *(bf16x4*)(xg + (size_t)row * HID + tid * 4) = o;
}

// ---------------- Fused transpose+convert for all 3 weights ----------------
// z in [0,24): z<8 -> wg (HIDxISZ), z<16 -> wu, z>=16 -> wd (ISZxHID)
__global__ __launch_bounds__(256) void tcvt_all_kernel(
    const float* __restrict__ wg, const float* __restrict__ wu, const float* __restrict__ wd,
    __bf16* __restrict__ wgT, __bf16* __restrict__ wuT, __bf16* __restrict__ wdT)
{
    const int z = blockIdx.z;
    const int e = z & 7;
    const float* in;
    __bf16* out;
    int R, C, r0, c0;
    if (z < 16) {
        R = HID; C = ISZ;
        r0 = blockIdx.y * 64; c0 = blockIdx.x * 64;   // y:16, x:22
        in  = (z < 8 ? wg : wu)  + (size_t)e * R * C;
        out = (z < 8 ? wgT : wuT) + (size_t)e * R * C;
    } else {
        R = ISZ; C = HID;
        r0 = blockIdx.x * 64; c0 = blockIdx.y * 64;   // x:22, y:16
        in  = wd  + (size_t)e * R * C;
        out = wdT + (size_t)e * R * C;
    }
    __shared__ float t[64][65];
    const int tid = threadIdx.x;
    const int lr  = tid >> 4;          // 0..15
    const int lc4 = (tid & 15) * 4;
    #pragma unroll
    for (int p = 0; p < 4; ++p) {
        float4 v = *(const float4*)(in + (size_t)(r0 + p * 16 + lr) * C + c0 + lc4);
        t[p * 16 + lr][lc4 + 0] = v.x;
        t[p * 16 + lr][lc4 + 1] = v.y;
        t[p * 16 + lr][lc4 + 2] = v.z;
        t[p * 16 + lr][lc4 + 3] = v.w;
    }
    __syncthreads();
    #pragma unroll
    for (int p = 0; p < 4; ++p) {
        int oc = p * 16 + lr;          // local in-col index = out-row
        bf16x4 w;
        #pragma unroll
        for (int j = 0; j < 4; ++j) w[j] = (__bf16)t[lc4 + j][oc];
        *(bf16x4*)(out + (size_t)(c0 + oc) * R + r0 + lc4) = w;
    }
}

// ---------------- FFN1: inter = silu(xg@WgT') * (xg@WuT') ----------------
// BM=64 x BN=64(G)+64(U), BK=64, 4 waves 2x2, 3-buf 2-ahead counted-vmcnt pipeline,
// 8-chunk XOR swizzle (src + read involution), XCD-chunked block swizzle, setprio MFMA.
__global__ __launch_bounds__(256) void ffn1_kernel(
    const __bf16* __restrict__ xg,
    const __bf16* __restrict__ wgT, const __bf16* __restrict__ wuT,
    const int* __restrict__ offs, const int* __restrict__ ncnt,
    __bf16* __restrict__ inter)
{
    // flat grid 5632 = 8 XCD chunks of 704; consecutive per-XCD blocks share (e,i0) weight panel
    const int n  = blockIdx.x;
    const int nn = (n & 7) * 704 + (n >> 3);
    const int i0 = (nn >> 8) * 64;          // 22 stripes
    const int xr = nn & 255;
    const int e  = xr >> 5;
    const int rt = xr & 31;
    if (rt * 64 >= ncnt[e]) return;
    const int rowbase = offs[e] + rt * 64;

    __shared__ __bf16 sA[3][64][64];   // 24 KB
    __shared__ __bf16 sG[3][64][64];   // 24 KB
    __shared__ __bf16 sU[3][64][64];   // 24 KB

    const int tid  = threadIdx.x;
    const int lane = tid & 63;
    const int wid  = tid >> 6;
    const int wr = wid >> 1, wc = wid & 1;
    const int kh = lane >> 4;          // 0..3
    const int ml = lane & 15;

    // staging: one gload16 covers 8 rows x 128B; LDS chunk (lane&7) of row (lane>>3)
    // holds global chunk (lane&7)^(lane>>3)  (involution within 8-row stripe)
    const int s8 = lane >> 3;                       // 0..7
    const int cswz = ((lane & 7) ^ s8) * 8;         // swizzled source col (bf16 elems)
    const __bf16* Ab = xg + (size_t)(rowbase + wid * 16 + s8) * HID + cswz;
    const size_t woff = (size_t)e * ISZ * HID + (size_t)(i0 + wid * 16 + s8) * HID + cswz;
    const __bf16* Gb = wgT + woff;
    const __bf16* Ub = wuT + woff;
    const size_t rstep = (size_t)8 * HID;           // +8 rows

    f32x4 accg[2][2], accu[2][2];
    #pragma unroll
    for (int m = 0; m < 2; ++m)
        #pragma unroll
        for (int q = 0; q < 2; ++q) { accg[m][q] = (f32x4){0,0,0,0}; accu[m][q] = (f32x4){0,0,0,0}; }

    auto stage = [&](int b, int k0) {   // 6 gload16 per wave
        gload16(Ab + k0,         &sA[b][wid * 16][0]);
        gload16(Ab + k0 + rstep, &sA[b][wid * 16 + 8][0]);
        gload16(Gb + k0,         &sG[b][wid * 16][0]);
        gload16(Gb + k0 + rstep, &sG[b][wid * 16 + 8][0]);
        gload16(Ub + k0,         &sU[b][wid * 16][0]);
        gload16(Ub + k0 + rstep, &sU[b][wid * 16 + 8][0]);
    };
    auto compute = [&](int b) {
        bf16x8 a_[2][2], g_[2][2], u_[2][2];   // [frag][k-half]
        #pragma unroll
        for (int m = 0; m < 2; ++m)
            #pragma unroll
            for (int h = 0; h < 2; ++h)
                a_[m][h] = *(const bf16x8*)&sA[b][wr * 32 + m * 16 + ml][((kh + 4 * h) ^ (ml & 7)) * 8];
        #pragma unroll
        for (int q = 0; q < 2; ++q)
            #pragma unroll
            for (int h = 0; h < 2; ++h) {
                g_[q][h] = *(const bf16x8*)&sG[b][wc * 32 + q * 16 + ml][((kh + 4 * h) ^ (ml & 7)) * 8];
                u_[q][h] = *(const bf16x8*)&sU[b][wc * 32 + q * 16 + ml][((kh + 4 * h) ^ (ml & 7)) * 8];
            }
        __builtin_amdgcn_s_setprio(1);
        #pragma unroll
        for (int m = 0; m < 2; ++m)
            #pragma unroll
            for (int q = 0; q < 2; ++q)
                #pragma unroll
                for (int h = 0; h < 2; ++h) {
                    accg[m][q] = __builtin_amdgcn_mfma_f32_16x16x32_bf16(a_[m][h], g_[q][h], accg[m][q], 0, 0, 0);
                    accu[m][q] = __builtin_amdgcn_mfma_f32_16x16x32_bf16(a_[m][h], u_[q][h], accu[m][q], 0, 0, 0);
                }
        __builtin_amdgcn_s_setprio(0);
    };

    const int nIter = HID / 64;   // 16
    stage(0, 0);
    stage(1, 64);
    PIPE_BARRIER(6)               // stage0 done -> buf0 ready; stage1 (6 loads) in flight
    for (int i = 0; i < nIter; ++i) {
        int ks = (i + 2 < nIter) ? (i + 2) * 64 : 0;   // clamped dead stage keeps counts uniform
        stage((i + 2) % 3, ks);
        compute(i % 3);
        PIPE_BARRIER(6)           // newest stage in flight; buf i+1 ready; ds_reads drained
    }

    #pragma unroll
    for (int m = 0; m < 2; ++m)
        #pragma unroll
        for (int q = 0; q < 2; ++q)
            #pragma unroll
            for (int r = 0; r < 4; ++r) {
                float gv = accg[m][q][r];
                float uv = accu[m][q][r];
                float v = gv / (1.0f + __expf(-gv)) * uv;
                int row = rowbase + wr * 32 + m * 16 + kh * 4 + r;  // D row = (lane>>4)*4 + reg
                int col = i0 + wc * 32 + q * 16 + ml;               // D col = lane&15
                inter[(size_t)row * ISZ + col] = (__bf16)v;
            }
}

// ---------------- FFN2: y[row] = rwt[row] * (inter[row] @ WdT')  (no atomics) ----------------
// BM=64 x BN=64, BK=64, 4 waves 2x2, 3-buf 2-ahead pipeline, same swizzles.
__global__ __launch_bounds__(256) void ffn2_kernel(
    const __bf16* __restrict__ inter, const __bf16* __restrict__ wdT,
    const float* __restrict__ rwt,
    const int* __restrict__ offs, const int* __restrict__ ncnt,
    float* __restrict__ y)
{
    // flat grid 4096 = 8 XCD chunks of 512
    const int n  = blockIdx.x;
    const int nn = (n & 7) * 512 + (n >> 3);
    const int n0 = (nn >> 8) * 64;          // 16 stripes
    const int xr = nn & 255;
    const int e  = xr >> 5;
    const int rt = xr & 31;
    if (rt * 64 >= ncnt[e]) return;
    const int rowbase = offs[e] + rt * 64;

    __shared__ __bf16 sA[3][64][64];   // 24 KB
    __shared__ __bf16 sB[3][64][64];   // 24 KB

    const int tid  = threadIdx.x;
    const int lane = tid & 63;
    const int wid  = tid >> 6;
    const int wr = wid >> 1, wc = wid & 1;
    const int kh = lane >> 4;
    const int ml = lane & 15;

    const int s8 = lane >> 3;
    const int cswz = ((lane & 7) ^ s8) * 8;
    const __bf16* Ab = inter + (size_t)(rowbase + wid * 16 + s8) * ISZ + cswz;
    const __bf16* Bb = wdT + (size_t)e * HID * ISZ + (size_t)(n0 + wid * 16 + s8) * ISZ + cswz;
    const size_t rstep = (size_t)8 * ISZ;

    f32x4 acc[2][2];
    #pragma unroll
    for (int m = 0; m < 2; ++m)
        #pragma unroll
        for (int q = 0; q < 2; ++q) acc[m][q] = (f32x4){0,0,0,0};

    auto stage = [&](int b, int k0) {   // 4 gload16 per wave
        gload16(Ab + k0,         &sA[b][wid * 16][0]);
        gload16(Ab + k0 + rstep, &sA[b][wid * 16 + 8][0]);
        gload16(Bb + k0,         &sB[b][wid * 16][0]);
        gload16(Bb + k0 + rstep, &sB[b][wid * 16 + 8][0]);
    };
    auto compute = [&](int b) {
        bf16x8 a_[2][2], b_[2][2];
        #pragma unroll
        for (int m = 0; m < 2; ++m)
            #pragma unroll
            for (int h = 0; h < 2; ++h)
                a_[m][h] = *(const bf16x8*)&sA[b][wr * 32 + m * 16 + ml][((kh + 4 * h) ^ (ml & 7)) * 8];
        #pragma unroll
        for (int q = 0; q < 2; ++q)
            #pragma unroll
            for (int h = 0; h < 2; ++h)
                b_[q][h] = *(const bf16x8*)&sB[b][wc * 32 + q * 16 + ml][((kh + 4 * h) ^ (ml & 7)) * 8];
        __builtin_amdgcn_s_setprio(1);
        #pragma unroll
        for (int m = 0; m < 2; ++m)
            #pragma unroll
            for (int q = 0; q < 2; ++q)
                #pragma unroll
                for (int h = 0; h < 2; ++h)
                    acc[m][q] = __builtin_amdgcn_mfma_f32_16x16x32_bf16(a_[m][h], b_[q][h], acc[m][q], 0, 0, 0);
        __builtin_amdgcn_s_setprio(0);
    };

    const int nIter = ISZ / 64;   // 22
    stage(0, 0);
    stage(1, 64);
    PIPE_BARRIER(4)
    for (int i = 0; i < nIter; ++i) {
        int ks = (i + 2 < nIter) ? (i + 2) * 64 : 0;
        stage((i + 2) % 3, ks);
        compute(i % 3);
        PIPE_BARRIER(4)
    }

    #pragma unroll
    for (int m = 0; m < 2; ++m)
        #pragma unroll
        for (int q = 0; q < 2; ++q)
            #pragma unroll
            for (int r = 0; r < 4; ++r) {
                int row = rowbase + wr * 32 + m * 16 + kh * 4 + r;
                float v = rwt[row] * acc[m][q][r];
                y[(size_t)row * HID + n0 + wc * 32 + q * 16 + ml] = v;
            }
}

// ---------------- Combine: out[t] = y[row0(t)] + y[row1(t)] ----------------
__global__ __launch_bounds__(256) void combine_kernel(
    const float* __restrict__ y, const int* __restrict__ tok2row, float* __restrict__ out)
{
    const int idx = blockIdx.x * 256 + threadIdx.x;   // over T_TOKENS * HID/4
    const int t = idx >> 8;           // HID/4 = 256 float4 per token
    const int c = (idx & 255) * 4;
    const int r0 = tok2row[t * 2];
    const int r1 = tok2row[t * 2 + 1];
    float4 a = *(const float4*)(y + (size_t)r0 * HID + c);
    float4 b = *(const float4*)(y + (size_t)r1 * HID + c);
    float4 o = {a.x + b.x, a.y + b.y, a.z + b.z, a.w + b.w};
    *(float4*)(out + (size_t)t * HID + c) = o;
}

extern "C" void kernel_launch(void* const* d_in, const int* in_sizes, int n_in,
                              void* d_out, int out_size, void* d_ws, size_t ws_size,
                              hipStream_t stream) {
    const float* x  = (const float*)d_in[0];
    const float* gw = (const float*)d_in[1];
    const float* wg = (const float*)d_in[2];
    const float* wu = (const float*)d_in[3];
    const float* wd = (const float*)d_in[4];
    float* out = (float*)d_out;

    char* ws = (char*)d_ws;
    int*    counts  = (int*)(ws + 0);
    int*    cursor  = (int*)(ws + 32);
    int*    offs    = (int*)(ws + 64);
    int*    ncnt    = (int*)(ws + 96);
    int*    sel     = (int*)(ws + 128);                 // 4096 int
    float*  wtp     = (float*)(ws + 16512);             // 4096 f32
    int*    rtok    = (int*)(ws + 32896);               // 5120 int
    float*  rwt     = (float*)(ws + 53376);             // 5120 f32
    int*    tok2row = (int*)(ws + 73856);               // 4096 int
    __bf16* xg      = (__bf16*)(ws + 90240);            // 5120*1024 bf16 = 10.49 MB
    __bf16* inter   = (__bf16*)(ws + 10576000);         // 5120*1408 bf16 = 14.42 MB
    __bf16* wgT     = (__bf16*)(ws + 24993920);         // 8*1408*1024 bf16 = 23.07 MB
    __bf16* wuT     = (__bf16*)(ws + 48062592);         // 23.07 MB
    __bf16* wdT     = (__bf16*)(ws + 71131264);         // 23.07 MB -> total 94.2 MB
    float*  y       = (float*)wgT;                      // alias: wgT dead after ffn1; 21.0 MB <= 23.07 MB

    hipMemsetAsync(counts, 0, 32, stream);
    hipMemsetAsync(rtok, 0xFF, RROWS * 4, stream);

    tcvt_all_kernel<<<dim3(ISZ / 64, HID / 64, 24), 256, 0, stream>>>(wg, wu, wd, wgT, wuT, wdT);

    router_kernel<<<T_TOKENS / 4, 256, 0, stream>>>(x, gw, sel, wtp, counts);
    scan_kernel<<<1, 64, 0, stream>>>(counts, offs, ncnt, cursor);
    assign_kernel<<<(T_TOKENS + 255) / 256, 256, 0, stream>>>(sel, wtp, offs, cursor, rtok, rwt, tok2row);
    gather_kernel<<<RROWS, 256, 0, stream>>>(x, rtok, xg);

    ffn1_kernel<<<8 * 704, 256, 0, stream>>>(xg, wgT, wuT, offs, ncnt, inter);   // 5632 = 256 x 22
    ffn2_kernel<<<8 * 512, 256, 0, stream>>>(inter, wdT, rwt, offs, ncnt, y);    // 4096 = 256 x 16
    combine_kernel<<<(T_TOKENS * HID / 4) / 256, 256, 0, stream>>>(y, tok2row, out);
}